// Round 7
// baseline (225.000 us; speedup 1.0000x reference)
//
#include <hip/hip_runtime.h>
#include <hip/hip_bf16.h>
#include <math.h>

// Fused MLP 256->64->16->4 + global softmax over flattened [B*4].
//
// Layer 1 via bf16 MFMA (16x16x32), 3-term split precision (verified R5):
//   x*w ~= xh*wh + xl*wh + xh*wl   (xl*wl ~2^-18 dropped)
// R7: m97-style x staging. Per block (256 rows, 8 waves): K-loop of 8 steps
// of 32 floats; each step the block cooperatively loads the next 256x32 x-tile
// (fully coalesced, fire-and-forget into regs), computes on the current LDS
// buffer, then ds_writes the next buffer and barriers ONCE. Latency is hidden
// by the full-step lookahead (~3000 cyc >> 900 cyc HBM), not by occupancy.
// xbuf row stride 36 dw (16B-aligned; b128 reads/writes land 8 lanes per
// 4-bank window = structural optimum). wlds: w1 hi+lo bf16, [n][k], row
// stride 260 dw. LDS ~145 KB -> 1 block/CU, launch_bounds(512,2) -> VGPR<=256.
// Epilogue (verified R5): hs stride 68 reusing xbuf, layer-2/3 2 threads/row,
// exp unnormalized + 1 atomic/block; norm_kernel scales by 1/S.

typedef __attribute__((ext_vector_type(8))) short bf16x8;  // 8 bf16 = 4 VGPRs
typedef __attribute__((ext_vector_type(4))) float f32x4;

#define WKD 260   // wlds row stride in dwords (520 shorts)
#define XS  36    // xbuf row stride in floats
#define HSS 68    // hs row stride in floats
#define NBLOCKS 512   // 131072 / 256 rows per block

__device__ __forceinline__ short f2bf(float v) {
    unsigned u = __float_as_uint(v);
    unsigned r = (u + 0x7FFFu + ((u >> 16) & 1u)) >> 16;
    return (short)r;
}
__device__ __forceinline__ float bf2f(short s) {
    return __uint_as_float(((unsigned)(unsigned short)s) << 16);
}

__device__ __forceinline__ void cvt8(const float4 v0, const float4 v1,
                                     bf16x8& ah, bf16x8& al)
{
    const float f[8] = {v0.x, v0.y, v0.z, v0.w, v1.x, v1.y, v1.z, v1.w};
    unsigned* ahp = (unsigned*)&ah;
    unsigned* alp = (unsigned*)&al;
#pragma unroll
    for (int p = 0; p < 4; ++p) {
        float2 fp = make_float2(f[2 * p], f[2 * p + 1]);
        __hip_bfloat162 h2 = __float22bfloat162_rn(fp);   // v_cvt_pk_bf16_f32
        float2 hf = __bfloat1622float2(h2);
        __hip_bfloat162 l2 =
            __float22bfloat162_rn(make_float2(fp.x - hf.x, fp.y - hf.y));
        union { __hip_bfloat162 b; unsigned u; } ch, cl;
        ch.b = h2; cl.b = l2;
        ahp[p] = ch.u;
        alp[p] = cl.u;
    }
}

__global__ __launch_bounds__(512, 2)
void mlp_kernel(const float* __restrict__ x, const float* __restrict__ w1,
                const float* __restrict__ b1, const float* __restrict__ w2,
                const float* __restrict__ b2, const float* __restrict__ w3,
                const float* __restrict__ b3, float* __restrict__ out,
                float* __restrict__ wsum)
{
    __shared__ __align__(16) short wlds[64 * 2 * WKD];        // 66560 B
    __shared__ __align__(16) float xbuf[2][256 * XS];         // 73728 B (reused as hs)
    __shared__ float ws2[64 * 16];
    __shared__ float ws3[64];
    __shared__ float bs1[64];
    __shared__ float bsum[8];
    float* hs = xbuf[0];   // epilogue alias: 256*HSS*4 = 69632 <= 73728

    const int tid  = threadIdx.x;
    const int lane = tid & 63;
    const int wid  = tid >> 6;    // 0..7
    const int quad = lane >> 4;   // 0..3
    const int m16  = lane & 15;
    const int row0 = blockIdx.x * 256;

    // ---- x staging geometry (per lane, fixed) ----
    const int srow = lane >> 3;          // 0..7 within an 8-row chunk
    const int scol = (lane & 7) * 4;     // float offset within 32-float step
    // chunk q (0..3): rows wid*32 + q*8 + srow
    const float* gx[4];
    int lx[4];
#pragma unroll
    for (int q = 0; q < 4; ++q) {
        const int rl = wid * 32 + q * 8 + srow;
        gx[q] = x + (size_t)(row0 + rl) * 256 + scol;
        lx[q] = rl * XS + scol;
    }

    // ---- prologue: issue step-0 x loads, then stage weights ----
    float4 pre[4];
#pragma unroll
    for (int q = 0; q < 4; ++q) pre[q] = *(const float4*)(gx[q]);

    for (int i = tid; i < 1024; i += 512) ws2[i] = w2[i];
    if (tid < 64) ws3[tid] = w3[tid];
    if (tid >= 64 && tid < 128) bs1[tid - 64] = b1[tid - 64];
    {
        const int n  = tid & 63;
        const int kb = (tid >> 6) * 4;
        for (int kk = kb; kk < 256; kk += 32) {
            const float v0 = w1[(size_t)(kk + 0) * 64 + n];
            const float v1 = w1[(size_t)(kk + 1) * 64 + n];
            const float v2 = w1[(size_t)(kk + 2) * 64 + n];
            const float v3 = w1[(size_t)(kk + 3) * 64 + n];
            short4 hi, lo;
            hi.x = f2bf(v0); lo.x = f2bf(v0 - bf2f(hi.x));
            hi.y = f2bf(v1); lo.y = f2bf(v1 - bf2f(hi.y));
            hi.z = f2bf(v2); lo.z = f2bf(v2 - bf2f(hi.z));
            hi.w = f2bf(v3); lo.w = f2bf(v3 - bf2f(hi.w));
            short* wrow = wlds + n * 2 * WKD;          // 520 shorts per n
            *(short4*)&wrow[kk]       = hi;            // hi at k
            *(short4*)&wrow[256 + kk] = lo;            // lo at 256 + k
        }
    }
    // write step-0 tile
#pragma unroll
    for (int q = 0; q < 4; ++q) *(float4*)&xbuf[0][lx[q]] = pre[q];
    __syncthreads();

    // ---- K-loop: 8 steps of 32 ----
    f32x4 acc[2][4];
#pragma unroll
    for (int mt = 0; mt < 2; ++mt)
#pragma unroll
        for (int t = 0; t < 4; ++t) acc[mt][t] = (f32x4)0.0f;

#pragma unroll
    for (int s = 0; s < 8; ++s) {
        const int b = s & 1;
        float4 nx[4];
        if (s < 7) {   // fire next-step loads (no dependency until ds_write)
#pragma unroll
            for (int q = 0; q < 4; ++q)
                nx[q] = *(const float4*)(gx[q] + (s + 1) * 32);
        }

        bf16x8 bh[4], bl[4];
#pragma unroll
        for (int t = 0; t < 4; ++t) {  // B-frag: n = t*16+m16, k = quad*8+j
            const short* bp = wlds + (t * 16 + m16) * 2 * WKD
                                   + s * 32 + quad * 8;
            bh[t] = *(const bf16x8*)bp;
            bl[t] = *(const bf16x8*)(bp + 256);
        }
#pragma unroll
        for (int mt = 0; mt < 2; ++mt) {
            // A-frag from LDS: row = wid*32 + mt*16 + m16, k = quad*8+j
            const float* xp = &xbuf[b][(wid * 32 + mt * 16 + m16) * XS + quad * 8];
            const float4 v0 = *(const float4*)xp;
            const float4 v1 = *(const float4*)(xp + 4);
            bf16x8 ah, al;
            cvt8(v0, v1, ah, al);
#pragma unroll
            for (int t = 0; t < 4; ++t)
                acc[mt][t] = __builtin_amdgcn_mfma_f32_16x16x32_bf16(
                    ah, bh[t], acc[mt][t], 0, 0, 0);
#pragma unroll
            for (int t = 0; t < 4; ++t)
                acc[mt][t] = __builtin_amdgcn_mfma_f32_16x16x32_bf16(
                    al, bh[t], acc[mt][t], 0, 0, 0);
#pragma unroll
            for (int t = 0; t < 4; ++t)
                acc[mt][t] = __builtin_amdgcn_mfma_f32_16x16x32_bf16(
                    ah, bl[t], acc[mt][t], 0, 0, 0);
        }

        if (s < 7) {
#pragma unroll
            for (int q = 0; q < 4; ++q)
                *(float4*)&xbuf[1 - b][lx[q]] = nx[q];   // waits vmcnt
            __syncthreads();   // next buffer complete for all waves
        }
    }
    __syncthreads();   // everyone done with xbuf/wlds -> reuse as hs

    // ---- bias + relu -> h stash (C/D: col = t*16+m16, row = quad*4+r) ----
#pragma unroll
    for (int mt = 0; mt < 2; ++mt)
#pragma unroll
        for (int t = 0; t < 4; ++t) {
            const float bc = bs1[t * 16 + m16];
#pragma unroll
            for (int r = 0; r < 4; ++r) {
                const int rr = wid * 32 + mt * 16 + quad * 4 + r;
                hs[rr * HSS + t * 16 + m16] = fmaxf(acc[mt][t][r] + bc, 0.0f);
            }
        }
    __syncthreads();

    // ---- layers 2/3: 2 threads per row, 8 z2-cols each ----
    const int r2 = tid >> 1;
    const int jq = (tid & 1) * 8;
    float z2[8];
#pragma unroll
    for (int jj = 0; jj < 8; ++jj) z2[jj] = b2[jq + jj];
#pragma unroll 4
    for (int c = 0; c < 64; c += 4) {
        const float4 h4 = *(const float4*)&hs[r2 * HSS + c];
        const float hv[4] = {h4.x, h4.y, h4.z, h4.w};
#pragma unroll
        for (int i = 0; i < 4; ++i)
#pragma unroll
            for (int jj = 0; jj < 8; ++jj)
                z2[jj] = fmaf(hv[i], ws2[(c + i) * 16 + jq + jj], z2[jj]);
    }
    float l0 = 0.f, l1 = 0.f, l2 = 0.f, l3 = 0.f;
#pragma unroll
    for (int jj = 0; jj < 8; ++jj) {
        const float th = tanhf(z2[jj]);
        const int j = jq + jj;
        l0 = fmaf(th, ws3[j * 4 + 0], l0);
        l1 = fmaf(th, ws3[j * 4 + 1], l1);
        l2 = fmaf(th, ws3[j * 4 + 2], l2);
        l3 = fmaf(th, ws3[j * 4 + 3], l3);
    }
    l0 += __shfl_xor(l0, 1); l1 += __shfl_xor(l1, 1);
    l2 += __shfl_xor(l2, 1); l3 += __shfl_xor(l3, 1);

    float s = 0.0f;
    if ((tid & 1) == 0) {
        const float e0 = expf(l0 + b3[0]);
        const float e1 = expf(l1 + b3[1]);
        const float e2 = expf(l2 + b3[2]);
        const float e3 = expf(l3 + b3[3]);
        *(float4*)&out[(size_t)(row0 + r2) * 4] =
            make_float4(e0, e1, e2, e3);
        s = e0 + e1 + e2 + e3;
    }
#pragma unroll
    for (int off = 1; off < 64; off <<= 1) s += __shfl_xor(s, off);
    if (lane == 0) bsum[wid] = s;
    __syncthreads();
    if (tid == 0) {
        float tot = 0.0f;
#pragma unroll
        for (int i = 0; i < 8; ++i) tot += bsum[i];
        atomicAdd(wsum, tot);
    }
}

__global__ __launch_bounds__(256)
void norm_kernel(float4* __restrict__ out, const float* __restrict__ wsum, int n4)
{
    const int i = blockIdx.x * 256 + threadIdx.x;
    if (i < n4) {
        const float inv = 1.0f / *wsum;
        float4 v = out[i];
        v.x *= inv; v.y *= inv; v.z *= inv; v.w *= inv;
        out[i] = v;
    }
}

extern "C" void kernel_launch(void* const* d_in, const int* in_sizes, int n_in,
                              void* d_out, int out_size, void* d_ws, size_t ws_size,
                              hipStream_t stream) {
    (void)in_sizes; (void)n_in; (void)ws_size;
    const float* x  = (const float*)d_in[0];
    const float* w1 = (const float*)d_in[1];
    const float* b1 = (const float*)d_in[2];
    const float* w2 = (const float*)d_in[3];
    const float* b2 = (const float*)d_in[4];
    const float* w3 = (const float*)d_in[5];
    const float* b3 = (const float*)d_in[6];
    float* out  = (float*)d_out;
    float* wsum = (float*)d_ws;

    hipMemsetAsync(wsum, 0, sizeof(float), stream);
    mlp_kernel<<<NBLOCKS, 512, 0, stream>>>(x, w1, b1, w2, b2, w3, b3, out, wsum);
    const int n4 = out_size >> 2;
    norm_kernel<<<(n4 + 255) / 256, 256, 0, stream>>>((float4*)out, wsum, n4);
}